// Round 4
// baseline (206.006 us; speedup 1.0000x reference)
//
#include <hip/hip_runtime.h>
#include <hip/hip_bf16.h>

typedef __hip_bfloat16 bf16;
typedef __attribute__((ext_vector_type(8))) short short8;
typedef __attribute__((ext_vector_type(4))) float f32x4;

#define SS 512
#define HD 768
#define NEGC (-1e30f)
#define NSPLIT 8
#define TOK 64                       // SS / NSPLIT
#define POOL_BLOCKS 768              // 48 groups * 2 batch * 8 splits
#define NCONV 128                    // W f32->bf16 conversion blocks
#define D1_BLOCKS (POOL_BLOCKS + 4 + NCONV)

// ---------------------------------------------------------------------------
// f32x8 -> bf16x8 in-register convert
// ---------------------------------------------------------------------------
__device__ __forceinline__ short8 cvt8(float4 a, float4 b)
{
  union { bf16 h[8]; short8 s; } u;
  u.h[0] = __hip_bfloat16(a.x); u.h[1] = __hip_bfloat16(a.y);
  u.h[2] = __hip_bfloat16(a.z); u.h[3] = __hip_bfloat16(a.w);
  u.h[4] = __hip_bfloat16(b.x); u.h[5] = __hip_bfloat16(b.y);
  u.h[6] = __hip_bfloat16(b.z); u.h[7] = __hip_bfloat16(b.w);
  return u.s;
}

struct WC { const float* s; bf16* d; int n8; };
struct WC6 { WC c[6]; };

// ---------------------------------------------------------------------------
// Dispatch 1: pool partials (bx<768) | aux (4 blocks) | W bf16 convert (128).
// Pool: 8 spans, 64 tokens (split sp of 8), 768 h = 3 consecutive h/thread.
// NOTE (round-3 post-mortem): 16 spans/block regressed ~10us — 48 live f32
// accumulators spill; d1 is VALU/occupancy-bound, not emb-traffic-bound
// (L3 absorbs the re-reads). Keep 8 spans / 24 accumulators.
// ---------------------------------------------------------------------------
__global__ __launch_bounds__(256) void k_d1(
    const int* __restrict__ e_masks, const int* __restrict__ m_masks,
    const int* __restrict__ r_masks, const int* __restrict__ c_masks,
    const float* __restrict__ emb, const int* __restrict__ input_ids,
    const int* __restrict__ esizes, const int* __restrict__ msizes,
    const float* __restrict__ nsemb, const float* __restrict__ esemb,
    bf16* __restrict__ part, int* __restrict__ flags,
    bf16* __restrict__ sze, bf16* __restrict__ szm,
    bf16* __restrict__ ctxb, float* __restrict__ out, WC6 wc)
{
  int bx = blockIdx.x;
  int t  = threadIdx.x;

  if (bx >= POOL_BLOCKS) {
    int q = bx - POOL_BLOCKS;
    if (q == 0) {            // entity size-emb table [128][32] bf16
      for (int i = t; i < 128 * 32; i += 256)
        sze[i] = __hip_bfloat16(nsemb[(size_t)esizes[i >> 5] * 32 + (i & 31)]);
    } else if (q == 1) {     // mention size-emb table
      for (int i = t; i < 128 * 32; i += 256)
        szm[i] = __hip_bfloat16(esemb[(size_t)msizes[i >> 5] * 32 + (i & 31)]);
    } else if (q == 2) {     // bf16 cls-ctx rows, both batches
      __shared__ int s_cls;
      for (int b2 = 0; b2 < 2; b2++) {
        if (t == 0) s_cls = SS;
        __syncthreads();
        for (int s = t; s < SS; s += 256)
          if (input_ids[b2 * SS + s] == 101) atomicMin(&s_cls, s);
        __syncthreads();
        int ci = (s_cls == SS) ? 0 : s_cls;
        for (int hh = t; hh < HD; hh += 256)
          ctxb[(size_t)b2 * HD + hh] = __hip_bfloat16(emb[((size_t)b2 * SS + ci) * HD + hh]);
        __syncthreads();
      }
    } else if (q == 3) {     // zero d_out (3840 floats) for head atomics
      for (int i = t; i < 3840; i += 256) out[i] = 0.f;
    } else {                 // W f32 -> bf16 conversion, grid-stride per seg
      int cid = q - 4;
      #pragma unroll
      for (int seg = 0; seg < 6; seg++) {
        const float* s = wc.c[seg].s;
        bf16* dp = wc.c[seg].d;
        int n8 = wc.c[seg].n8;
        for (int i = cid * 256 + t; i < n8; i += NCONV * 256) {
          float4 f0 = *(const float4*)(s + (size_t)i * 8);
          float4 f1 = *(const float4*)(s + (size_t)i * 8 + 4);
          *(short8*)(dp + (size_t)i * 8) = cvt8(f0, f1);
        }
      }
    }
    return;
  }

  // ---------------- pooling partials ----------------
  int g  = bx % 48;              // span group (8 spans)
  int b  = (bx / 48) & 1;        // batch
  int sp = bx / 96;              // S-split 0..7 (64 tokens each)
  int j0 = g * 8;

  const int* marr; int row0;
  if      (j0 < 64)  { marr = e_masks; row0 = b*64  +  j0;        }
  else if (j0 < 128) { marr = m_masks; row0 = b*64  + (j0-64);    }
  else if (j0 < 256) { marr = r_masks; row0 = b*128 + (j0-128);   }
  else               { marr = c_masks; row0 = b*128 + (j0-256);   }

  __shared__ unsigned s_pack[TOK];
  __shared__ unsigned s_any;
  if (t == 0) s_any = 0u;
  __syncthreads();

  int sbase = sp * TOK;
  if (t < TOK) {
    unsigned w = 0;
    #pragma unroll
    for (int k = 0; k < 8; k++) {
      int mm = marr[(size_t)(row0 + k) * SS + sbase + t];
      w |= (mm != 0 ? 1u : 0u) << k;
    }
    s_pack[t] = w;
    atomicOr(&s_any, w);
  }
  __syncthreads();

  float a0[8], a1[8], a2[8];
  #pragma unroll
  for (int k = 0; k < 8; k++) { a0[k] = -INFINITY; a1[k] = -INFINITY; a2[k] = -INFINITY; }

  // 3 consecutive h per thread -> one 12B load per token; 2 tokens per step.
  const float* ep = emb + ((size_t)b * SS + sbase) * HD + t * 3;
  #pragma unroll 2
  for (int s = 0; s < TOK; s += 2) {
    float u0 = ep[0];
    float u1 = ep[1];
    float u2 = ep[2];
    float v0 = ep[HD];
    float v1 = ep[HD + 1];
    float v2 = ep[HD + 2];
    ep += 2 * HD;
    unsigned w0 = (unsigned)__builtin_amdgcn_readfirstlane((int)s_pack[s]);
    unsigned w1 = (unsigned)__builtin_amdgcn_readfirstlane((int)s_pack[s + 1]);
    #pragma unroll
    for (int k = 0; k < 8; k++) {
      float add0 = (w0 & (1u << k)) ? 0.f : NEGC;   // uniform: s_cselect
      float add1 = (w1 & (1u << k)) ? 0.f : NEGC;
      a0[k] = fmaxf(fmaxf(a0[k], u0 + add0), v0 + add1);   // v_max3_f32
      a1[k] = fmaxf(fmaxf(a1[k], u1 + add0), v1 + add1);
      a2[k] = fmaxf(fmaxf(a2[k], u2 + add0), v2 + add1);
    }
  }

  #pragma unroll
  for (int k = 0; k < 8; k++) {
    int sg = b * 384 + j0 + k;
    bf16* dst = part + ((size_t)sg * NSPLIT + sp) * HD + t * 3;
    dst[0] = __hip_bfloat16(a0[k]);
    dst[1] = __hip_bfloat16(a1[k]);
    dst[2] = __hip_bfloat16(a2[k]);
  }
  if (t < 8) flags[(size_t)(b * 384 + j0 + t) * NSPLIT + sp] = (int)((s_any >> t) & 1u);
}

// ---------------------------------------------------------------------------
// Dispatch 2: combine the 8 S-split partials -> final bf16 pools / ctx.
// ---------------------------------------------------------------------------
__global__ __launch_bounds__(256) void k_combine(
    const bf16* __restrict__ part, const int* __restrict__ flags,
    bf16* __restrict__ epool, bf16* __restrict__ mpool,
    bf16* __restrict__ rctx, bf16* __restrict__ cctx)
{
  int sg = blockIdx.x;
  int b = sg / 384, j = sg % 384;
  int any = 0;
  #pragma unroll
  for (int sp = 0; sp < NSPLIT; sp++) any |= flags[(size_t)sg * NSPLIT + sp];

  int h = threadIdx.x * 3;
  float v0 = -INFINITY, v1 = -INFINITY, v2 = -INFINITY;
  #pragma unroll
  for (int sp = 0; sp < NSPLIT; sp++) {
    const bf16* src = part + ((size_t)sg * NSPLIT + sp) * HD + h;
    v0 = fmaxf(v0, (float)src[0]);
    v1 = fmaxf(v1, (float)src[1]);
    v2 = fmaxf(v2, (float)src[2]);
  }
  bf16* dst;
  if      (j < 64)  { dst = epool + ((size_t)b*64  + j)       * HD + h; }
  else if (j < 128) { dst = mpool + ((size_t)b*64  + (j-64))  * HD + h; }
  else if (j < 256) { dst = rctx  + ((size_t)b*128 + (j-128)) * HD + h;
                      if (!any) { v0 = 0.f; v1 = 0.f; v2 = 0.f; } }
  else              { dst = cctx  + ((size_t)b*128 + (j-256)) * HD + h;
                      if (!any) { v0 = 0.f; v1 = 0.f; v2 = 0.f; } }
  dst[0] = __hip_bfloat16(v0);
  dst[1] = __hip_bfloat16(v1);
  dst[2] = __hip_bfloat16(v2);
}

// ---------------------------------------------------------------------------
// GEMM layer 1: A gathered bf16, W bf16. M-tile = 16 rows (was 32): doubles
// block count -> 4.5 live blocks/CU for latency hiding (kernel is L2-latency
// bound, not BW/compute bound: ~2.5 GFLOP total, ~12 MB fetch). 1-D grid
// id = x*96 + (y+24z); blocks sharing a W panel differ by 96 (0 mod 8) ->
// same XCD L2. 4 waves K-split + LDS reduce; span problems (z<2) fuse head
// via f32 atomicAdd.
// ---------------------------------------------------------------------------
struct P1 {
  const bf16 *ctx, *pool, *sz; const int* ridx;
  const bf16* W; const float* bias;
  bf16* C;                 // null for span problems
  const float *hw, *hb; float* outp;
  int is_rel, N, K, Mtiles;   // Mtiles in units of 16 rows
};
struct P1x4 { P1 p[4]; };

__global__ __launch_bounds__(256, 2) void k_gemm1(P1x4 args)
{
  int id = blockIdx.x;
  int x = id / 96;
  int r96 = id % 96;
  int y = r96 % 24, z = r96 / 24;
  P1 g = args.p[z];
  if (x >= g.Mtiles) return;
  int mt = x * 16, nt = y * 32;
  int wave = threadIdx.x >> 6, lane = threadIdx.x & 63;
  int lm = lane & 15, quad = lane >> 4;
  int K_ = g.K;

  const bf16 *g0, *g1, *g2, *g3, *g4;
  {
    int rI = mt + lm;
    if (g.is_rel) {
      int b = rI >> 7;
      int i0 = g.ridx[2 * rI], i1 = g.ridx[2 * rI + 1];
      g0 = g.ctx  + (size_t)rI * HD;
      g1 = g.pool + (size_t)(b * 64 + i0) * HD;
      g2 = g.pool + (size_t)(b * 64 + i1) * HD;
      g3 = g.sz   + (size_t)(b * 64 + i0) * 32;
      g4 = g.sz   + (size_t)(b * 64 + i1) * 32;
    } else {
      g0 = g.ctx  + (size_t)(rI >> 6) * HD;
      g1 = g.pool + (size_t)rI * HD;
      g2 = g.sz   + (size_t)rI * 32;
      g3 = g2; g4 = g2;
    }
  }
  const bf16* w0p = g.W + (size_t)(nt + lm)      * K_ + quad * 8;
  const bf16* w1p = g.W + (size_t)(nt + 16 + lm) * K_ + quad * 8;

  f32x4 acc00 = {0.f,0.f,0.f,0.f}, acc01 = {0.f,0.f,0.f,0.f};

  for (int k32 = wave * 32; k32 < K_; k32 += 128) {
    const bf16* b0;
    if      (k32 < 768)  { b0 = g0 + k32;          }
    else if (k32 < 1536) { b0 = g1 + (k32 - 768);  }
    else if (k32 < 2304) { b0 = g2 + (k32 - 1536); }
    else if (k32 < 2336) { b0 = g3 + (k32 - 2304); }
    else                 { b0 = g4 + (k32 - 2336); }
    short8 a0 = *(const short8*)((const short*)b0 + quad * 8);
    short8 w0 = *(const short8*)(w0p + k32);
    short8 w1 = *(const short8*)(w1p + k32);
    acc00 = __builtin_amdgcn_mfma_f32_16x16x32_bf16(a0, w0, acc00, 0, 0, 0);
    acc01 = __builtin_amdgcn_mfma_f32_16x16x32_bf16(a0, w1, acc01, 0, 0, 0);
  }

  __shared__ float smem[4 * 16 * 32];
  #pragma unroll
  for (int reg = 0; reg < 4; reg++) {
    int rI = quad * 4 + reg;
    smem[wave*512 + rI*32 + lm]      = acc00[reg];
    smem[wave*512 + rI*32 + 16 + lm] = acc01[reg];
  }
  __syncthreads();

  int c = threadIdx.x & 31;
  int rb = threadIdx.x >> 5;
  float bb = g.bias[nt + c];
  #pragma unroll
  for (int i = 0; i < 2; i++) {
    int rI = rb + 8 * i;
    float v = smem[rI*32 + c] + smem[512 + rI*32 + c] + smem[1024 + rI*32 + c] + smem[1536 + rI*32 + c];
    v = fmaxf(v + bb, 0.f);
    if (g.C) g.C[(size_t)(mt + rI) * HD + nt + c] = __hip_bfloat16(v);
    else     smem[rI*32 + c] = v;
  }
  __syncthreads();

  if (!g.C) {   // fused span head (16 rows x 16 threads each)
    int rI = threadIdx.x >> 4, oi = threadIdx.x & 15;
    for (int o = oi; o < g.N; o += 16) {
      float s = 0.f;
      #pragma unroll
      for (int cc = 0; cc < 32; cc++) {
        int c2 = (cc + rI) & 31;
        s += smem[rI*32 + c2] * g.hw[(size_t)o * HD + nt + c2];
      }
      if (y == 0) s += g.hb[o];
      atomicAdd(g.outp + (size_t)(mt + rI) * g.N + o, s);
    }
  }
}

// ---------------------------------------------------------------------------
// GEMM layer 2: A bf16 contiguous, W bf16, fused rel/cr heads. M-tile 16,
// 1-D grid id = x*48 + (y+24z) (panel pinning, 48%8==0). 768 blocks.
// ---------------------------------------------------------------------------
struct P2 { const short* A; const bf16* W; const float* bias;
            const float *hw, *hb; float* outp; int N; };
struct P2x2 { P2 p[2]; };

__global__ __launch_bounds__(256, 2) void k_gemm2(P2x2 args)
{
  int id = blockIdx.x;
  int x = id / 48;
  int r48 = id % 48;
  int y = r48 % 24, z = r48 / 24;
  P2 g = args.p[z];
  int mt = x * 16, nt = y * 32;
  int wave = threadIdx.x >> 6, lane = threadIdx.x & 63;
  int lm = lane & 15, quad = lane >> 4;

  const short* a0p = g.A + (size_t)(mt + lm)      * HD + quad * 8;
  const bf16* w0p = g.W + (size_t)(nt + lm)      * HD + quad * 8;
  const bf16* w1p = g.W + (size_t)(nt + 16 + lm) * HD + quad * 8;

  f32x4 acc00 = {0.f,0.f,0.f,0.f}, acc01 = {0.f,0.f,0.f,0.f};

  for (int k32 = wave * 32; k32 < HD; k32 += 128) {
    short8 a0 = *(const short8*)(a0p + k32);
    short8 w0 = *(const short8*)(w0p + k32);
    short8 w1 = *(const short8*)(w1p + k32);
    acc00 = __builtin_amdgcn_mfma_f32_16x16x32_bf16(a0, w0, acc00, 0, 0, 0);
    acc01 = __builtin_amdgcn_mfma_f32_16x16x32_bf16(a0, w1, acc01, 0, 0, 0);
  }

  __shared__ float smem[4 * 16 * 32];
  #pragma unroll
  for (int reg = 0; reg < 4; reg++) {
    int rI = quad * 4 + reg;
    smem[wave*512 + rI*32 + lm]      = acc00[reg];
    smem[wave*512 + rI*32 + 16 + lm] = acc01[reg];
  }
  __syncthreads();

  int c = threadIdx.x & 31;
  int rb = threadIdx.x >> 5;
  float bb = g.bias[nt + c];
  #pragma unroll
  for (int i = 0; i < 2; i++) {
    int rI = rb + 8 * i;
    float v = smem[rI*32 + c] + smem[512 + rI*32 + c] + smem[1024 + rI*32 + c] + smem[1536 + rI*32 + c];
    smem[rI*32 + c] = fmaxf(v + bb, 0.f);
  }
  __syncthreads();

  int rI = threadIdx.x >> 4, oi = threadIdx.x & 15;
  for (int o = oi; o < g.N; o += 16) {
    float s = 0.f;
    #pragma unroll
    for (int cc = 0; cc < 32; cc++) {
      int c2 = (cc + rI) & 31;
      s += smem[rI*32 + c2] * g.hw[(size_t)o * HD + nt + c2];
    }
    if (y == 0) s += g.hb[o];
    atomicAdd(g.outp + (size_t)(mt + rI) * g.N + o, s);
  }
}

// ---------------------------------------------------------------------------
extern "C" void kernel_launch(void* const* d_in, const int* in_sizes, int n_in,
                              void* d_out, int out_size, void* d_ws, size_t ws_size,
                              hipStream_t stream)
{
  const int*   input_ids  = (const int*)d_in[0];
  const int*   e_masks    = (const int*)d_in[1];
  const int*   e_sizes    = (const int*)d_in[2];
  const int*   m_masks    = (const int*)d_in[3];
  const int*   m_sizes    = (const int*)d_in[4];
  const int*   relations  = (const int*)d_in[5];
  const int*   r_masks    = (const int*)d_in[6];
  const int*   references = (const int*)d_in[7];
  const int*   c_masks    = (const int*)d_in[8];
  const float* emb        = (const float*)d_in[9];
  const float* nsemb      = (const float*)d_in[10];
  const float* esemb      = (const float*)d_in[11];
  const float* ner_rep_w  = (const float*)d_in[12];
  const float* ner_rep_b  = (const float*)d_in[13];
  const float* ner_head_w = (const float*)d_in[14];
  const float* ner_head_b = (const float*)d_in[15];
  const float* emd_rep_w  = (const float*)d_in[16];
  const float* emd_rep_b  = (const float*)d_in[17];
  const float* emd_head_w = (const float*)d_in[18];
  const float* emd_head_b = (const float*)d_in[19];
  const float* rel_w1 = (const float*)d_in[20];
  const float* rel_b1 = (const float*)d_in[21];
  const float* rel_w2 = (const float*)d_in[22];
  const float* rel_b2 = (const float*)d_in[23];
  const float* rel_w3 = (const float*)d_in[24];
  const float* rel_b3 = (const float*)d_in[25];
  const float* cr_w1 = (const float*)d_in[26];
  const float* cr_b1 = (const float*)d_in[27];
  const float* cr_w2 = (const float*)d_in[28];
  const float* cr_b2 = (const float*)d_in[29];
  const float* cr_w3 = (const float*)d_in[30];
  const float* cr_b3 = (const float*)d_in[31];
  float* out = (float*)d_out;

  // ---- workspace carve ----
  bf16* wsb = (bf16*)d_ws;
  size_t ob = 0;
  bf16* PART  = wsb + ob; ob += (size_t)NSPLIT * 768 * HD;
  bf16* EPOOL = wsb + ob; ob += (size_t)128 * HD;
  bf16* MPOOL = wsb + ob; ob += (size_t)128 * HD;
  bf16* RCTX  = wsb + ob; ob += (size_t)256 * HD;
  bf16* CCTX  = wsb + ob; ob += (size_t)256 * HD;
  bf16* SZE   = wsb + ob; ob += (size_t)128 * 32;
  bf16* SZM   = wsb + ob; ob += (size_t)128 * 32;
  bf16* CTXB  = wsb + ob; ob += (size_t)2 * HD;
  bf16* RH1   = wsb + ob; ob += (size_t)256 * HD;
  bf16* CH1   = wsb + ob; ob += (size_t)256 * HD;
  int*  FLAGS = (int*)(wsb + ob); ob += (size_t)2 * NSPLIT * 768;
  bf16* WB_NER = wsb + ob; ob += (size_t)HD * 1568;
  bf16* WB_EMD = wsb + ob; ob += (size_t)HD * 1568;
  bf16* WB_RW1 = wsb + ob; ob += (size_t)HD * 2368;
  bf16* WB_CW1 = wsb + ob; ob += (size_t)HD * 2368;
  bf16* WB_RW2 = wsb + ob; ob += (size_t)HD * HD;
  bf16* WB_CW2 = wsb + ob; ob += (size_t)HD * HD;

  WC6 wc;
  wc.c[0] = { ner_rep_w, WB_NER, HD * 1568 / 8 };
  wc.c[1] = { emd_rep_w, WB_EMD, HD * 1568 / 8 };
  wc.c[2] = { rel_w1,    WB_RW1, HD * 2368 / 8 };
  wc.c[3] = { cr_w1,     WB_CW1, HD * 2368 / 8 };
  wc.c[4] = { rel_w2,    WB_RW2, HD * HD / 8 };
  wc.c[5] = { cr_w2,     WB_CW2, HD * HD / 8 };

  // 1) pool partials + aux + W convert
  k_d1<<<D1_BLOCKS, 256, 0, stream>>>(
      e_masks, m_masks, r_masks, c_masks, emb, input_ids,
      e_sizes, m_sizes, nsemb, esemb,
      PART, FLAGS, SZE, SZM, CTXB, out, wc);

  // 2) combine
  k_combine<<<768, 256, 0, stream>>>(PART, FLAGS, EPOOL, MPOOL, RCTX, CCTX);

  // 3) GEMM layer 1 (gathered A, bf16 W) + fused span heads, M-tile 16
  P1x4 a1;
  a1.p[0] = { CTXB, EPOOL, SZE, nullptr,    WB_NER, ner_rep_b,
              nullptr, ner_head_w, ner_head_b, out,        0, 10, 1568, 8 };
  a1.p[1] = { CTXB, MPOOL, SZM, nullptr,    WB_EMD, emd_rep_b,
              nullptr, emd_head_w, emd_head_b, out + 3328, 0, 2,  1568, 8 };
  a1.p[2] = { RCTX, EPOOL, SZE, relations,  WB_RW1, rel_b1,
              RH1, nullptr, nullptr, nullptr,              1, 0,  2368, 16 };
  a1.p[3] = { CCTX, MPOOL, SZM, references, WB_CW1, cr_b1,
              CH1, nullptr, nullptr, nullptr,              1, 0,  2368, 16 };
  k_gemm1<<<16 * 96, 256, 0, stream>>>(a1);

  // 4) GEMM layer 2 (bf16 W) + fused rel/cr heads, M-tile 16
  P2x2 a2;
  a2.p[0] = { (const short*)RH1, WB_RW2, rel_b2, rel_w3, rel_b3, out + 1280, 8 };
  a2.p[1] = { (const short*)CH1, WB_CW2, cr_b2,  cr_w3,  cr_b3,  out + 3584, 1 };
  k_gemm2<<<16 * 48, 256, 0, stream>>>(a2);
}

// Round 6
// 194.073 us; speedup vs baseline: 1.0615x; 1.0615x over previous
//
#include <hip/hip_runtime.h>
#include <hip/hip_bf16.h>

typedef __hip_bfloat16 bf16;
typedef __attribute__((ext_vector_type(8))) short short8;
typedef __attribute__((ext_vector_type(4))) float f32x4;

#define SS 512
#define HD 768
#define NEGC (-1e30f)
#define NSPLIT 8
#define TOK 64                       // SS / NSPLIT
#define POOL_BLOCKS 768              // 48 groups * 2 batch * 8 splits
#define NCONV 128                    // W f32->bf16 conversion blocks
#define D1_BLOCKS (POOL_BLOCKS + 4 + NCONV)

// ---------------------------------------------------------------------------
// f32x8 -> bf16x8 in-register convert
// ---------------------------------------------------------------------------
__device__ __forceinline__ short8 cvt8(float4 a, float4 b)
{
  union { bf16 h[8]; short8 s; } u;
  u.h[0] = __hip_bfloat16(a.x); u.h[1] = __hip_bfloat16(a.y);
  u.h[2] = __hip_bfloat16(a.z); u.h[3] = __hip_bfloat16(a.w);
  u.h[4] = __hip_bfloat16(b.x); u.h[5] = __hip_bfloat16(b.y);
  u.h[6] = __hip_bfloat16(b.z); u.h[7] = __hip_bfloat16(b.w);
  return u.s;
}

struct WC { const float* s; bf16* d; int n8; };
struct WC6 { WC c[6]; };

// ---------------------------------------------------------------------------
// Dispatch 1: pool partials (bx<768) | aux (4 blocks) | W bf16 convert (128).
// Pool: 8 spans, 64 tokens (split sp of 8), 768 h = 3 consecutive h/thread.
// POST-MORTEMS: (r3) 16 spans/block -> 48 acc spill, ~+10us. d1 is NOT
// emb-traffic-bound (emb = 3.1 MB, L2-resident). Keep 8 spans.
// ---------------------------------------------------------------------------
__global__ __launch_bounds__(256) void k_d1(
    const int* __restrict__ e_masks, const int* __restrict__ m_masks,
    const int* __restrict__ r_masks, const int* __restrict__ c_masks,
    const float* __restrict__ emb, const int* __restrict__ input_ids,
    const int* __restrict__ esizes, const int* __restrict__ msizes,
    const float* __restrict__ nsemb, const float* __restrict__ esemb,
    bf16* __restrict__ part, int* __restrict__ flags,
    bf16* __restrict__ sze, bf16* __restrict__ szm,
    bf16* __restrict__ ctxb, float* __restrict__ out, WC6 wc)
{
  int bx = blockIdx.x;
  int t  = threadIdx.x;

  if (bx >= POOL_BLOCKS) {
    int q = bx - POOL_BLOCKS;
    if (q == 0) {            // entity size-emb table [128][32] bf16
      for (int i = t; i < 128 * 32; i += 256)
        sze[i] = __hip_bfloat16(nsemb[(size_t)esizes[i >> 5] * 32 + (i & 31)]);
    } else if (q == 1) {     // mention size-emb table
      for (int i = t; i < 128 * 32; i += 256)
        szm[i] = __hip_bfloat16(esemb[(size_t)msizes[i >> 5] * 32 + (i & 31)]);
    } else if (q == 2) {     // bf16 cls-ctx rows, both batches
      __shared__ int s_cls;
      for (int b2 = 0; b2 < 2; b2++) {
        if (t == 0) s_cls = SS;
        __syncthreads();
        for (int s = t; s < SS; s += 256)
          if (input_ids[b2 * SS + s] == 101) atomicMin(&s_cls, s);
        __syncthreads();
        int ci = (s_cls == SS) ? 0 : s_cls;
        for (int hh = t; hh < HD; hh += 256)
          ctxb[(size_t)b2 * HD + hh] = __hip_bfloat16(emb[((size_t)b2 * SS + ci) * HD + hh]);
        __syncthreads();
      }
    } else if (q == 3) {     // zero d_out (3840 floats) for head atomics
      for (int i = t; i < 3840; i += 256) out[i] = 0.f;
    } else {                 // W f32 -> bf16 conversion, grid-stride per seg
      int cid = q - 4;
      #pragma unroll
      for (int seg = 0; seg < 6; seg++) {
        const float* s = wc.c[seg].s;
        bf16* dp = wc.c[seg].d;
        int n8 = wc.c[seg].n8;
        for (int i = cid * 256 + t; i < n8; i += NCONV * 256) {
          float4 f0 = *(const float4*)(s + (size_t)i * 8);
          float4 f1 = *(const float4*)(s + (size_t)i * 8 + 4);
          *(short8*)(dp + (size_t)i * 8) = cvt8(f0, f1);
        }
      }
    }
    return;
  }

  // ---------------- pooling partials ----------------
  int g  = bx % 48;              // span group (8 spans)
  int b  = (bx / 48) & 1;        // batch
  int sp = bx / 96;              // S-split 0..7 (64 tokens each)
  int j0 = g * 8;

  const int* marr; int row0;
  if      (j0 < 64)  { marr = e_masks; row0 = b*64  +  j0;        }
  else if (j0 < 128) { marr = m_masks; row0 = b*64  + (j0-64);    }
  else if (j0 < 256) { marr = r_masks; row0 = b*128 + (j0-128);   }
  else               { marr = c_masks; row0 = b*128 + (j0-256);   }

  __shared__ unsigned s_pack[TOK];
  __shared__ unsigned s_any;
  if (t == 0) s_any = 0u;
  __syncthreads();

  int sbase = sp * TOK;
  if (t < TOK) {
    unsigned w = 0;
    #pragma unroll
    for (int k = 0; k < 8; k++) {
      int mm = marr[(size_t)(row0 + k) * SS + sbase + t];
      w |= (mm != 0 ? 1u : 0u) << k;
    }
    s_pack[t] = w;
    atomicOr(&s_any, w);
  }
  __syncthreads();

  float a0[8], a1[8], a2[8];
  #pragma unroll
  for (int k = 0; k < 8; k++) { a0[k] = -INFINITY; a1[k] = -INFINITY; a2[k] = -INFINITY; }

  // 3 consecutive h per thread -> one 12B load per token; 2 tokens per step.
  const float* ep = emb + ((size_t)b * SS + sbase) * HD + t * 3;
  #pragma unroll 2
  for (int s = 0; s < TOK; s += 2) {
    float u0 = ep[0];
    float u1 = ep[1];
    float u2 = ep[2];
    float v0 = ep[HD];
    float v1 = ep[HD + 1];
    float v2 = ep[HD + 2];
    ep += 2 * HD;
    unsigned w0 = (unsigned)__builtin_amdgcn_readfirstlane((int)s_pack[s]);
    unsigned w1 = (unsigned)__builtin_amdgcn_readfirstlane((int)s_pack[s + 1]);
    #pragma unroll
    for (int k = 0; k < 8; k++) {
      float add0 = (w0 & (1u << k)) ? 0.f : NEGC;   // uniform: s_cselect
      float add1 = (w1 & (1u << k)) ? 0.f : NEGC;
      a0[k] = fmaxf(fmaxf(a0[k], u0 + add0), v0 + add1);   // v_max3_f32
      a1[k] = fmaxf(fmaxf(a1[k], u1 + add0), v1 + add1);
      a2[k] = fmaxf(fmaxf(a2[k], u2 + add0), v2 + add1);
    }
  }

  #pragma unroll
  for (int k = 0; k < 8; k++) {
    int sg = b * 384 + j0 + k;
    bf16* dst = part + ((size_t)sg * NSPLIT + sp) * HD + t * 3;
    dst[0] = __hip_bfloat16(a0[k]);
    dst[1] = __hip_bfloat16(a1[k]);
    dst[2] = __hip_bfloat16(a2[k]);
  }
  if (t < 8) flags[(size_t)(b * 384 + j0 + t) * NSPLIT + sp] = (int)((s_any >> t) & 1u);
}

// ---------------------------------------------------------------------------
// Dispatch 2: combine the 8 S-split partials -> final bf16 pools / ctx.
// ---------------------------------------------------------------------------
__global__ __launch_bounds__(256) void k_combine(
    const bf16* __restrict__ part, const int* __restrict__ flags,
    bf16* __restrict__ epool, bf16* __restrict__ mpool,
    bf16* __restrict__ rctx, bf16* __restrict__ cctx)
{
  int sg = blockIdx.x;
  int b = sg / 384, j = sg % 384;
  int any = 0;
  #pragma unroll
  for (int sp = 0; sp < NSPLIT; sp++) any |= flags[(size_t)sg * NSPLIT + sp];

  int h = threadIdx.x * 3;
  float v0 = -INFINITY, v1 = -INFINITY, v2 = -INFINITY;
  #pragma unroll
  for (int sp = 0; sp < NSPLIT; sp++) {
    const bf16* src = part + ((size_t)sg * NSPLIT + sp) * HD + h;
    v0 = fmaxf(v0, (float)src[0]);
    v1 = fmaxf(v1, (float)src[1]);
    v2 = fmaxf(v2, (float)src[2]);
  }
  bf16* dst;
  if      (j < 64)  { dst = epool + ((size_t)b*64  + j)       * HD + h; }
  else if (j < 128) { dst = mpool + ((size_t)b*64  + (j-64))  * HD + h; }
  else if (j < 256) { dst = rctx  + ((size_t)b*128 + (j-128)) * HD + h;
                      if (!any) { v0 = 0.f; v1 = 0.f; v2 = 0.f; } }
  else              { dst = cctx  + ((size_t)b*128 + (j-256)) * HD + h;
                      if (!any) { v0 = 0.f; v1 = 0.f; v2 = 0.f; } }
  dst[0] = __hip_bfloat16(v0);
  dst[1] = __hip_bfloat16(v1);
  dst[2] = __hip_bfloat16(v2);
}

// ---------------------------------------------------------------------------
// GEMM layer 1: A gathered bf16, W bf16. M-tile 32 (r4 post-mortem: 16
// doubled W traffic, +15us). Exact 576-block grid, offsets {0,96,192,384};
// within z: id = x*24 + y -> blocks sharing W panel (z,y) differ by 24
// (0 mod 8) -> same XCD L2; y spreads panels across XCDs. 1-deep K-prefetch:
// r1 counters (MfmaUtil 1.9, VALUBusy 6.4, Occ 17.7) show ~90% exposed-stall;
// issuing iter i+1's 3 loads before iter i's MFMAs overlaps L2/L3 latency.
// 4 waves K-split + LDS reduce; span problems (z<2) fuse head via atomicAdd.
// ---------------------------------------------------------------------------
struct P1 {
  const bf16 *ctx, *pool, *sz; const int* ridx;
  const bf16* W; const float* bias;
  bf16* C;                 // null for span problems
  const float *hw, *hb; float* outp;
  int is_rel, N, K, Mtiles;
};
struct P1x4 { P1 p[4]; };

__global__ __launch_bounds__(256, 2) void k_gemm1(P1x4 args)
{
  int id = blockIdx.x;
  int z, rem;
  if      (id < 96)  { z = 0; rem = id;       }
  else if (id < 192) { z = 1; rem = id - 96;  }
  else if (id < 384) { z = 2; rem = id - 192; }
  else               { z = 3; rem = id - 384; }
  int x = rem / 24, y = rem % 24;
  P1 g = args.p[z];
  int mt = x * 32, nt = y * 32;
  int wave = threadIdx.x >> 6, lane = threadIdx.x & 63;
  int lm = lane & 15, quad = lane >> 4;
  int K_ = g.K;

  const bf16 *g0[2], *g1[2], *g2[2], *g3[2], *g4[2];
  int rr[2] = { mt + lm, mt + 16 + lm };
  #pragma unroll
  for (int i = 0; i < 2; i++) {
    int rI = rr[i];
    if (g.is_rel) {
      int b = rI >> 7;
      int i0 = g.ridx[2 * rI], i1 = g.ridx[2 * rI + 1];
      g0[i] = g.ctx  + (size_t)rI * HD;
      g1[i] = g.pool + (size_t)(b * 64 + i0) * HD;
      g2[i] = g.pool + (size_t)(b * 64 + i1) * HD;
      g3[i] = g.sz   + (size_t)(b * 64 + i0) * 32;
      g4[i] = g.sz   + (size_t)(b * 64 + i1) * 32;
    } else {
      g0[i] = g.ctx  + (size_t)(rI >> 6) * HD;
      g1[i] = g.pool + (size_t)rI * HD;
      g2[i] = g.sz   + (size_t)rI * 32;
      g3[i] = g2[i]; g4[i] = g2[i];
    }
  }
  const bf16* w0p = g.W + (size_t)(nt + lm)      * K_ + quad * 8;
  const bf16* w1p = g.W + (size_t)(nt + 16 + lm) * K_ + quad * 8;

  f32x4 acc00 = {0.f,0.f,0.f,0.f}, acc01 = {0.f,0.f,0.f,0.f};
  f32x4 acc10 = {0.f,0.f,0.f,0.f}, acc11 = {0.f,0.f,0.f,0.f};

  auto ldA = [&](int kk, short8& a0, short8& a1) {
    const bf16 *b0, *b1;
    if      (kk < 768)  { b0 = g0[0] + kk;          b1 = g0[1] + kk;          }
    else if (kk < 1536) { b0 = g1[0] + (kk - 768);  b1 = g1[1] + (kk - 768);  }
    else if (kk < 2304) { b0 = g2[0] + (kk - 1536); b1 = g2[1] + (kk - 1536); }
    else if (kk < 2336) { b0 = g3[0] + (kk - 2304); b1 = g3[1] + (kk - 2304); }
    else                 { b0 = g4[0] + (kk - 2336); b1 = g4[1] + (kk - 2336); }
    a0 = *(const short8*)((const short*)b0 + quad * 8);
    a1 = *(const short8*)((const short*)b1 + quad * 8);
  };

  int k32 = wave * 32;
  short8 a0, a1, w0, w1;
  ldA(k32, a0, a1);
  w0 = *(const short8*)(w0p + k32);
  w1 = *(const short8*)(w1p + k32);
  for (int kn = k32 + 128; kn < K_; kn += 128) {
    short8 na0, na1, nw0, nw1;
    ldA(kn, na0, na1);                       // issue next loads before MFMAs
    nw0 = *(const short8*)(w0p + kn);
    nw1 = *(const short8*)(w1p + kn);
    acc00 = __builtin_amdgcn_mfma_f32_16x16x32_bf16(a0, w0, acc00, 0, 0, 0);
    acc01 = __builtin_amdgcn_mfma_f32_16x16x32_bf16(a0, w1, acc01, 0, 0, 0);
    acc10 = __builtin_amdgcn_mfma_f32_16x16x32_bf16(a1, w0, acc10, 0, 0, 0);
    acc11 = __builtin_amdgcn_mfma_f32_16x16x32_bf16(a1, w1, acc11, 0, 0, 0);
    a0 = na0; a1 = na1; w0 = nw0; w1 = nw1;
  }
  acc00 = __builtin_amdgcn_mfma_f32_16x16x32_bf16(a0, w0, acc00, 0, 0, 0);
  acc01 = __builtin_amdgcn_mfma_f32_16x16x32_bf16(a0, w1, acc01, 0, 0, 0);
  acc10 = __builtin_amdgcn_mfma_f32_16x16x32_bf16(a1, w0, acc10, 0, 0, 0);
  acc11 = __builtin_amdgcn_mfma_f32_16x16x32_bf16(a1, w1, acc11, 0, 0, 0);

  __shared__ float smem[4 * 32 * 32];
  #pragma unroll
  for (int reg = 0; reg < 4; reg++) {
    int rI = quad * 4 + reg;
    smem[wave*1024 + rI*32 + lm]             = acc00[reg];
    smem[wave*1024 + rI*32 + 16 + lm]        = acc01[reg];
    smem[wave*1024 + (16 + rI)*32 + lm]      = acc10[reg];
    smem[wave*1024 + (16 + rI)*32 + 16 + lm] = acc11[reg];
  }
  __syncthreads();

  int c = threadIdx.x & 31;
  int rb = threadIdx.x >> 5;
  float bb = g.bias[nt + c];
  #pragma unroll
  for (int i = 0; i < 4; i++) {
    int rI = rb + 8 * i;
    float v = smem[rI*32 + c] + smem[1024 + rI*32 + c] + smem[2048 + rI*32 + c] + smem[3072 + rI*32 + c];
    v = fmaxf(v + bb, 0.f);
    if (g.C) g.C[(size_t)(mt + rI) * HD + nt + c] = __hip_bfloat16(v);
    else     smem[rI*32 + c] = v;
  }
  __syncthreads();

  if (!g.C) {   // fused span head
    int rI = threadIdx.x >> 3, oi = threadIdx.x & 7;
    for (int o = oi; o < g.N; o += 8) {
      float s = 0.f;
      #pragma unroll
      for (int cc = 0; cc < 32; cc++) {
        int c2 = (cc + rI) & 31;
        s += smem[rI*32 + c2] * g.hw[(size_t)o * HD + nt + c2];
      }
      if (y == 0) s += g.hb[o];
      atomicAdd(g.outp + (size_t)(mt + rI) * g.N + o, s);
    }
  }
}

// ---------------------------------------------------------------------------
// GEMM layer 2: A bf16 contiguous, W bf16, fused rel/cr heads. M-tile 32,
// exact 384-block grid, id = x*48 + (y+24z) (panel pinning, 48%8==0).
// ---------------------------------------------------------------------------
struct P2 { const short* A; const bf16* W; const float* bias;
            const float *hw, *hb; float* outp; int N; };
struct P2x2 { P2 p[2]; };

__global__ __launch_bounds__(256, 2) void k_gemm2(P2x2 args)
{
  int id = blockIdx.x;
  int x = id / 48;
  int r48 = id % 48;
  int y = r48 % 24, z = r48 / 24;
  P2 g = args.p[z];
  int mt = x * 32, nt = y * 32;
  int wave = threadIdx.x >> 6, lane = threadIdx.x & 63;
  int lm = lane & 15, quad = lane >> 4;

  const short* a0p = g.A + (size_t)(mt + lm)      * HD + quad * 8;
  const short* a1p = g.A + (size_t)(mt + 16 + lm) * HD + quad * 8;
  const bf16* w0p = g.W + (size_t)(nt + lm)      * HD + quad * 8;
  const bf16* w1p = g.W + (size_t)(nt + 16 + lm) * HD + quad * 8;

  f32x4 acc00 = {0.f,0.f,0.f,0.f}, acc01 = {0.f,0.f,0.f,0.f};
  f32x4 acc10 = {0.f,0.f,0.f,0.f}, acc11 = {0.f,0.f,0.f,0.f};

  for (int k32 = wave * 32; k32 < HD; k32 += 128) {
    short8 a0 = *(const short8*)(a0p + k32);
    short8 a1 = *(const short8*)(a1p + k32);
    short8 w0 = *(const short8*)(w0p + k32);
    short8 w1 = *(const short8*)(w1p + k32);
    acc00 = __builtin_amdgcn_mfma_f32_16x16x32_bf16(a0, w0, acc00, 0, 0, 0);
    acc01 = __builtin_amdgcn_mfma_f32_16x16x32_bf16(a0, w1, acc01, 0, 0, 0);
    acc10 = __builtin_amdgcn_mfma_f32_16x16x32_bf16(a1, w0, acc10, 0, 0, 0);
    acc11 = __builtin_amdgcn_mfma_f32_16x16x32_bf16(a1, w1, acc11, 0, 0, 0);
  }

  __shared__ float smem[4 * 32 * 32];
  #pragma unroll
  for (int reg = 0; reg < 4; reg++) {
    int rI = quad * 4 + reg;
    smem[wave*1024 + rI*32 + lm]             = acc00[reg];
    smem[wave*1024 + rI*32 + 16 + lm]        = acc01[reg];
    smem[wave*1024 + (16 + rI)*32 + lm]      = acc10[reg];
    smem[wave*1024 + (16 + rI)*32 + 16 + lm] = acc11[reg];
  }
  __syncthreads();

  int c = threadIdx.x & 31;
  int rb = threadIdx.x >> 5;
  float bb = g.bias[nt + c];
  #pragma unroll
  for (int i = 0; i < 4; i++) {
    int rI = rb + 8 * i;
    float v = smem[rI*32 + c] + smem[1024 + rI*32 + c] + smem[2048 + rI*32 + c] + smem[3072 + rI*32 + c];
    smem[rI*32 + c] = fmaxf(v + bb, 0.f);
  }
  __syncthreads();

  int rI = threadIdx.x >> 3, oi = threadIdx.x & 7;
  for (int o = oi; o < g.N; o += 8) {
    float s = 0.f;
    #pragma unroll
    for (int cc = 0; cc < 32; cc++) {
      int c2 = (cc + rI) & 31;
      s += smem[rI*32 + c2] * g.hw[(size_t)o * HD + nt + c2];
    }
    if (y == 0) s += g.hb[o];
    atomicAdd(g.outp + (size_t)(mt + rI) * g.N + o, s);
  }
}

// ---------------------------------------------------------------------------
extern "C" void kernel_launch(void* const* d_in, const int* in_sizes, int n_in,
                              void* d_out, int out_size, void* d_ws, size_t ws_size,
                              hipStream_t stream)
{
  const int*   input_ids  = (const int*)d_in[0];
  const int*   e_masks    = (const int*)d_in[1];
  const int*   e_sizes    = (const int*)d_in[2];
  const int*   m_masks    = (const int*)d_in[3];
  const int*   m_sizes    = (const int*)d_in[4];
  const int*   relations  = (const int*)d_in[5];
  const int*   r_masks    = (const int*)d_in[6];
  const int*   references = (const int*)d_in[7];
  const int*   c_masks    = (const int*)d_in[8];
  const float* emb        = (const float*)d_in[9];
  const float* nsemb      = (const float*)d_in[10];
  const float* esemb      = (const float*)d_in[11];
  const float* ner_rep_w  = (const float*)d_in[12];
  const float* ner_rep_b  = (const float*)d_in[13];
  const float* ner_head_w = (const float*)d_in[14];
  const float* ner_head_b = (const float*)d_in[15];
  const float* emd_rep_w  = (const float*)d_in[16];
  const float* emd_rep_b  = (const float*)d_in[17];
  const float* emd_head_w = (const float*)d_in[18];
  const float* emd_head_b = (const float*)d_in[19];
  const float* rel_w1 = (const float*)d_in[20];
  const float* rel_b1 = (const float*)d_in[21];
  const float* rel_w2 = (const float*)d_in[22];
  const float* rel_b2 = (const float*)d_in[23];
  const float* rel_w3 = (const float*)d_in[24];
  const float* rel_b3 = (const float*)d_in[25];
  const float* cr_w1 = (const float*)d_in[26];
  const float* cr_b1 = (const float*)d_in[27];
  const float* cr_w2 = (const float*)d_in[28];
  const float* cr_b2 = (const float*)d_in[29];
  const float* cr_w3 = (const float*)d_in[30];
  const float* cr_b3 = (const float*)d_in[31];
  float* out = (float*)d_out;

  // ---- workspace carve ----
  bf16* wsb = (bf16*)d_ws;
  size_t ob = 0;
  bf16* PART  = wsb + ob; ob += (size_t)NSPLIT * 768 * HD;
  bf16* EPOOL = wsb + ob; ob += (size_t)128 * HD;
  bf16* MPOOL = wsb + ob; ob += (size_t)128 * HD;
  bf16* RCTX  = wsb + ob; ob += (size_t)256 * HD;
  bf16* CCTX  = wsb + ob; ob += (size_t)256 * HD;
  bf16* SZE   = wsb + ob; ob += (size_t)128 * 32;
  bf16* SZM   = wsb + ob; ob += (size_t)128 * 32;
  bf16* CTXB  = wsb + ob; ob += (size_t)2 * HD;
  bf16* RH1   = wsb + ob; ob += (size_t)256 * HD;
  bf16* CH1   = wsb + ob; ob += (size_t)256 * HD;
  int*  FLAGS = (int*)(wsb + ob); ob += (size_t)2 * NSPLIT * 768;
  bf16* WB_NER = wsb + ob; ob += (size_t)HD * 1568;
  bf16* WB_EMD = wsb + ob; ob += (size_t)HD * 1568;
  bf16* WB_RW1 = wsb + ob; ob += (size_t)HD * 2368;
  bf16* WB_CW1 = wsb + ob; ob += (size_t)HD * 2368;
  bf16* WB_RW2 = wsb + ob; ob += (size_t)HD * HD;
  bf16* WB_CW2 = wsb + ob; ob += (size_t)HD * HD;

  WC6 wc;
  wc.c[0] = { ner_rep_w, WB_NER, HD * 1568 / 8 };
  wc.c[1] = { emd_rep_w, WB_EMD, HD * 1568 / 8 };
  wc.c[2] = { rel_w1,    WB_RW1, HD * 2368 / 8 };
  wc.c[3] = { cr_w1,     WB_CW1, HD * 2368 / 8 };
  wc.c[4] = { rel_w2,    WB_RW2, HD * HD / 8 };
  wc.c[5] = { cr_w2,     WB_CW2, HD * HD / 8 };

  // 1) pool partials + aux + W convert
  k_d1<<<D1_BLOCKS, 256, 0, stream>>>(
      e_masks, m_masks, r_masks, c_masks, emb, input_ids,
      e_sizes, m_sizes, nsemb, esemb,
      PART, FLAGS, SZE, SZM, CTXB, out, wc);

  // 2) combine
  k_combine<<<768, 256, 0, stream>>>(PART, FLAGS, EPOOL, MPOOL, RCTX, CCTX);

  // 3) GEMM layer 1 (gathered A, bf16 W) + fused span heads, exact grid
  P1x4 a1;
  a1.p[0] = { CTXB, EPOOL, SZE, nullptr,    WB_NER, ner_rep_b,
              nullptr, ner_head_w, ner_head_b, out,        0, 10, 1568, 4 };
  a1.p[1] = { CTXB, MPOOL, SZM, nullptr,    WB_EMD, emd_rep_b,
              nullptr, emd_head_w, emd_head_b, out + 3328, 0, 2,  1568, 4 };
  a1.p[2] = { RCTX, EPOOL, SZE, relations,  WB_RW1, rel_b1,
              RH1, nullptr, nullptr, nullptr,              1, 0,  2368, 8 };
  a1.p[3] = { CCTX, MPOOL, SZM, references, WB_CW1, cr_b1,
              CH1, nullptr, nullptr, nullptr,              1, 0,  2368, 8 };
  k_gemm1<<<576, 256, 0, stream>>>(a1);

  // 4) GEMM layer 2 (bf16 W) + fused rel/cr heads, exact grid
  P2x2 a2;
  a2.p[0] = { (const short*)RH1, WB_RW2, rel_b2, rel_w3, rel_b3, out + 1280, 8 };
  a2.p[1] = { (const short*)CH1, WB_CW2, cr_b2,  cr_w3,  cr_b3,  out + 3584, 1 };
  k_gemm2<<<384, 256, 0, stream>>>(a2);
}

// Round 7
// 187.178 us; speedup vs baseline: 1.1006x; 1.0368x over previous
//
#include <hip/hip_runtime.h>
#include <hip/hip_bf16.h>

typedef __hip_bfloat16 bf16;
typedef __attribute__((ext_vector_type(8))) short short8;
typedef __attribute__((ext_vector_type(4))) float f32x4;

#define SS 512
#define HD 768
#define NEGC (-1e30f)
#define NSPLIT 8
#define TOK 64                       // SS / NSPLIT
#define POOL_BLOCKS 768              // 48 groups * 2 batch * 8 splits
#define NCONV 252                    // W fragment-convert blocks (768+4+252 = 1024 = 4/CU)
#define D1_BLOCKS (POOL_BLOCKS + 4 + NCONV)

// ---------------------------------------------------------------------------
// f32x8 -> bf16x8 in-register convert
// ---------------------------------------------------------------------------
__device__ __forceinline__ short8 cvt8(float4 a, float4 b)
{
  union { bf16 h[8]; short8 s; } u;
  u.h[0] = __hip_bfloat16(a.x); u.h[1] = __hip_bfloat16(a.y);
  u.h[2] = __hip_bfloat16(a.z); u.h[3] = __hip_bfloat16(a.w);
  u.h[4] = __hip_bfloat16(b.x); u.h[5] = __hip_bfloat16(b.y);
  u.h[6] = __hip_bfloat16(b.z); u.h[7] = __hip_bfloat16(b.w);
  return u.s;
}

struct WC { const float* s; bf16* d; int K; };
struct WC6 { WC c[6]; };

// ---------------------------------------------------------------------------
// Dispatch 1: pool partials (bx<768) | aux (4) | W fragment-convert (252).
// Pool: 8 spans, 64 tokens, 3 h/thread (r3 post-mortem: 16 spans spill).
// Convert emits FRAGMENT-MAJOR bf16 W: [nblk][kblk][16][4][8] so a gemm
// wave's W-load is one contiguous 1 KB transaction instead of a 16-row
// scatter (the r1-counter latency-stall theory). Units = (seg,nblk), no div.
// ---------------------------------------------------------------------------
__global__ __launch_bounds__(256) void k_d1(
    const int* __restrict__ e_masks, const int* __restrict__ m_masks,
    const int* __restrict__ r_masks, const int* __restrict__ c_masks,
    const float* __restrict__ emb, const int* __restrict__ input_ids,
    const int* __restrict__ esizes, const int* __restrict__ msizes,
    const float* __restrict__ nsemb, const float* __restrict__ esemb,
    bf16* __restrict__ part, int* __restrict__ flags,
    bf16* __restrict__ sze, bf16* __restrict__ szm,
    bf16* __restrict__ ctxb, float* __restrict__ out, WC6 wc)
{
  int bx = blockIdx.x;
  int t  = threadIdx.x;

  if (bx >= POOL_BLOCKS) {
    int q = bx - POOL_BLOCKS;
    if (q == 0) {            // entity size-emb table [128][32] bf16
      for (int i = t; i < 128 * 32; i += 256)
        sze[i] = __hip_bfloat16(nsemb[(size_t)esizes[i >> 5] * 32 + (i & 31)]);
    } else if (q == 1) {     // mention size-emb table
      for (int i = t; i < 128 * 32; i += 256)
        szm[i] = __hip_bfloat16(esemb[(size_t)msizes[i >> 5] * 32 + (i & 31)]);
    } else if (q == 2) {     // bf16 cls-ctx rows, both batches
      __shared__ int s_cls;
      for (int b2 = 0; b2 < 2; b2++) {
        if (t == 0) s_cls = SS;
        __syncthreads();
        for (int s = t; s < SS; s += 256)
          if (input_ids[b2 * SS + s] == 101) atomicMin(&s_cls, s);
        __syncthreads();
        int ci = (s_cls == SS) ? 0 : s_cls;
        for (int hh = t; hh < HD; hh += 256)
          ctxb[(size_t)b2 * HD + hh] = __hip_bfloat16(emb[((size_t)b2 * SS + ci) * HD + hh]);
        __syncthreads();
      }
    } else if (q == 3) {     // zero d_out (3840 floats) for head atomics
      for (int i = t; i < 3840; i += 256) out[i] = 0.f;
    } else {                 // fragment-major W convert: 6 segs * 48 nblks
      int cid = q - 4;
      for (int u = cid; u < 288; u += NCONV) {
        int seg = u / 48, nblk = u % 48;        // const div -> magic mul
        const float* s = wc.c[seg].s;
        bf16* dp = wc.c[seg].d;
        int K = wc.c[seg].K;
        int KB = K >> 5;
        int nchunk = K * 2;                     // (K/32)*512/8 chunks of 8
        const float* srow = s + (size_t)nblk * 16 * K;
        bf16* drow = dp + (size_t)nblk * KB * 512;
        for (int c8 = t; c8 < nchunk; c8 += 256) {
          int kblk = c8 >> 6;
          int lm   = (c8 >> 2) & 15;
          int quad = c8 & 3;
          const float* sp = srow + (size_t)lm * K + kblk * 32 + quad * 8;
          float4 f0 = *(const float4*)sp;
          float4 f1 = *(const float4*)(sp + 4);
          *(short8*)(drow + (size_t)kblk * 512 + lm * 32 + quad * 8) = cvt8(f0, f1);
        }
      }
    }
    return;
  }

  // ---------------- pooling partials ----------------
  int g  = bx % 48;              // span group (8 spans)
  int b  = (bx / 48) & 1;        // batch
  int sp = bx / 96;              // S-split 0..7 (64 tokens each)
  int j0 = g * 8;

  const int* marr; int row0;
  if      (j0 < 64)  { marr = e_masks; row0 = b*64  +  j0;        }
  else if (j0 < 128) { marr = m_masks; row0 = b*64  + (j0-64);    }
  else if (j0 < 256) { marr = r_masks; row0 = b*128 + (j0-128);   }
  else               { marr = c_masks; row0 = b*128 + (j0-256);   }

  __shared__ unsigned s_pack[TOK];
  __shared__ unsigned s_any;
  if (t == 0) s_any = 0u;
  __syncthreads();

  int sbase = sp * TOK;
  if (t < TOK) {
    unsigned w = 0;
    #pragma unroll
    for (int k = 0; k < 8; k++) {
      int mm = marr[(size_t)(row0 + k) * SS + sbase + t];
      w |= (mm != 0 ? 1u : 0u) << k;
    }
    s_pack[t] = w;
    atomicOr(&s_any, w);
  }
  __syncthreads();

  float a0[8], a1[8], a2[8];
  #pragma unroll
  for (int k = 0; k < 8; k++) { a0[k] = -INFINITY; a1[k] = -INFINITY; a2[k] = -INFINITY; }

  // 3 consecutive h per thread -> one 12B load per token; 2 tokens per step.
  const float* ep = emb + ((size_t)b * SS + sbase) * HD + t * 3;
  #pragma unroll 2
  for (int s = 0; s < TOK; s += 2) {
    float u0 = ep[0];
    float u1 = ep[1];
    float u2 = ep[2];
    float v0 = ep[HD];
    float v1 = ep[HD + 1];
    float v2 = ep[HD + 2];
    ep += 2 * HD;
    unsigned w0 = (unsigned)__builtin_amdgcn_readfirstlane((int)s_pack[s]);
    unsigned w1 = (unsigned)__builtin_amdgcn_readfirstlane((int)s_pack[s + 1]);
    #pragma unroll
    for (int k = 0; k < 8; k++) {
      float add0 = (w0 & (1u << k)) ? 0.f : NEGC;   // uniform: s_cselect
      float add1 = (w1 & (1u << k)) ? 0.f : NEGC;
      a0[k] = fmaxf(fmaxf(a0[k], u0 + add0), v0 + add1);   // v_max3_f32
      a1[k] = fmaxf(fmaxf(a1[k], u1 + add0), v1 + add1);
      a2[k] = fmaxf(fmaxf(a2[k], u2 + add0), v2 + add1);
    }
  }

  #pragma unroll
  for (int k = 0; k < 8; k++) {
    int sg = b * 384 + j0 + k;
    bf16* dst = part + ((size_t)sg * NSPLIT + sp) * HD + t * 3;
    dst[0] = __hip_bfloat16(a0[k]);
    dst[1] = __hip_bfloat16(a1[k]);
    dst[2] = __hip_bfloat16(a2[k]);
  }
  if (t < 8) flags[(size_t)(b * 384 + j0 + t) * NSPLIT + sp] = (int)((s_any >> t) & 1u);
}

// ---------------------------------------------------------------------------
// Dispatch 2: combine the 8 S-split partials -> final bf16 pools / ctx.
// ---------------------------------------------------------------------------
__global__ __launch_bounds__(256) void k_combine(
    const bf16* __restrict__ part, const int* __restrict__ flags,
    bf16* __restrict__ epool, bf16* __restrict__ mpool,
    bf16* __restrict__ rctx, bf16* __restrict__ cctx)
{
  int sg = blockIdx.x;
  int b = sg / 384, j = sg % 384;
  int any = 0;
  #pragma unroll
  for (int sp = 0; sp < NSPLIT; sp++) any |= flags[(size_t)sg * NSPLIT + sp];

  int h = threadIdx.x * 3;
  float v0 = -INFINITY, v1 = -INFINITY, v2 = -INFINITY;
  #pragma unroll
  for (int sp = 0; sp < NSPLIT; sp++) {
    const bf16* src = part + ((size_t)sg * NSPLIT + sp) * HD + h;
    v0 = fmaxf(v0, (float)src[0]);
    v1 = fmaxf(v1, (float)src[1]);
    v2 = fmaxf(v2, (float)src[2]);
  }
  bf16* dst;
  if      (j < 64)  { dst = epool + ((size_t)b*64  + j)       * HD + h; }
  else if (j < 128) { dst = mpool + ((size_t)b*64  + (j-64))  * HD + h; }
  else if (j < 256) { dst = rctx  + ((size_t)b*128 + (j-128)) * HD + h;
                      if (!any) { v0 = 0.f; v1 = 0.f; v2 = 0.f; } }
  else              { dst = cctx  + ((size_t)b*128 + (j-256)) * HD + h;
                      if (!any) { v0 = 0.f; v1 = 0.f; v2 = 0.f; } }
  dst[0] = __hip_bfloat16(v0);
  dst[1] = __hip_bfloat16(v1);
  dst[2] = __hip_bfloat16(v2);
}

// ---------------------------------------------------------------------------
// GEMM layer 1: A gathered bf16 row-major, W bf16 FRAGMENT-MAJOR
// ([nblk][kblk][16][4][8]): each wave W-load = contiguous 1 KB. Exact
// 576-block grid, offsets {0,96,192,384}; within z id = x*24 + y (panel
// pinning: blocks sharing a (z,y) W panel differ by 24 == 0 mod 8).
// Simple K-loop (r6: explicit prefetch was -3us; compiler schedules).
// Rel output C written FRAGMENT-MAJOR for gemm2's contiguous A-loads.
// ---------------------------------------------------------------------------
struct P1 {
  const bf16 *ctx, *pool, *sz; const int* ridx;
  const bf16* W; const float* bias;
  bf16* C;                 // null for span problems (fragment-major if set)
  const float *hw, *hb; float* outp;
  int is_rel, N, K, Mtiles;
};
struct P1x4 { P1 p[4]; };

__global__ __launch_bounds__(256, 2) void k_gemm1(P1x4 args)
{
  int id = blockIdx.x;
  int z, rem;
  if      (id < 96)  { z = 0; rem = id;       }
  else if (id < 192) { z = 1; rem = id - 96;  }
  else if (id < 384) { z = 2; rem = id - 192; }
  else               { z = 3; rem = id - 384; }
  int x = rem / 24, y = rem % 24;
  P1 g = args.p[z];
  int mt = x * 32, nt = y * 32;
  int wave = threadIdx.x >> 6, lane = threadIdx.x & 63;
  int lm = lane & 15, quad = lane >> 4;
  int K_ = g.K;
  int KB = K_ >> 5;

  const bf16 *g0[2], *g1[2], *g2[2], *g3[2], *g4[2];
  int rr[2] = { mt + lm, mt + 16 + lm };
  #pragma unroll
  for (int i = 0; i < 2; i++) {
    int rI = rr[i];
    if (g.is_rel) {
      int b = rI >> 7;
      int i0 = g.ridx[2 * rI], i1 = g.ridx[2 * rI + 1];
      g0[i] = g.ctx  + (size_t)rI * HD;
      g1[i] = g.pool + (size_t)(b * 64 + i0) * HD;
      g2[i] = g.pool + (size_t)(b * 64 + i1) * HD;
      g3[i] = g.sz   + (size_t)(b * 64 + i0) * 32;
      g4[i] = g.sz   + (size_t)(b * 64 + i1) * 32;
    } else {
      g0[i] = g.ctx  + (size_t)(rI >> 6) * HD;
      g1[i] = g.pool + (size_t)rI * HD;
      g2[i] = g.sz   + (size_t)rI * 32;
      g3[i] = g2[i]; g4[i] = g2[i];
    }
  }
  // fragment-major W: nblk = nt/16 = 2y (lm covers 16 rows), +1 for second
  const bf16* w0p = g.W + (size_t)(nt >> 4) * KB * 512 + lm * 32 + quad * 8;
  const bf16* w1p = w0p + (size_t)KB * 512;

  f32x4 acc00 = {0.f,0.f,0.f,0.f}, acc01 = {0.f,0.f,0.f,0.f};
  f32x4 acc10 = {0.f,0.f,0.f,0.f}, acc11 = {0.f,0.f,0.f,0.f};

  for (int k32 = wave * 32; k32 < K_; k32 += 128) {
    const bf16 *b0, *b1;
    if      (k32 < 768)  { b0 = g0[0] + k32;          b1 = g0[1] + k32;          }
    else if (k32 < 1536) { b0 = g1[0] + (k32 - 768);  b1 = g1[1] + (k32 - 768);  }
    else if (k32 < 2304) { b0 = g2[0] + (k32 - 1536); b1 = g2[1] + (k32 - 1536); }
    else if (k32 < 2336) { b0 = g3[0] + (k32 - 2304); b1 = g3[1] + (k32 - 2304); }
    else                 { b0 = g4[0] + (k32 - 2336); b1 = g4[1] + (k32 - 2336); }
    short8 a0 = *(const short8*)((const short*)b0 + quad * 8);
    short8 a1 = *(const short8*)((const short*)b1 + quad * 8);
    short8 w0 = *(const short8*)(w0p + (size_t)k32 * 16);   // (k32/32)*512
    short8 w1 = *(const short8*)(w1p + (size_t)k32 * 16);
    acc00 = __builtin_amdgcn_mfma_f32_16x16x32_bf16(a0, w0, acc00, 0, 0, 0);
    acc01 = __builtin_amdgcn_mfma_f32_16x16x32_bf16(a0, w1, acc01, 0, 0, 0);
    acc10 = __builtin_amdgcn_mfma_f32_16x16x32_bf16(a1, w0, acc10, 0, 0, 0);
    acc11 = __builtin_amdgcn_mfma_f32_16x16x32_bf16(a1, w1, acc11, 0, 0, 0);
  }

  __shared__ float smem[4 * 32 * 32];
  #pragma unroll
  for (int reg = 0; reg < 4; reg++) {
    int rI = quad * 4 + reg;
    smem[wave*1024 + rI*32 + lm]             = acc00[reg];
    smem[wave*1024 + rI*32 + 16 + lm]        = acc01[reg];
    smem[wave*1024 + (16 + rI)*32 + lm]      = acc10[reg];
    smem[wave*1024 + (16 + rI)*32 + 16 + lm] = acc11[reg];
  }
  __syncthreads();

  int c = threadIdx.x & 31;
  int rb = threadIdx.x >> 5;
  float bb = g.bias[nt + c];
  #pragma unroll
  for (int i = 0; i < 4; i++) {
    int rI = rb + 8 * i;
    float v = smem[rI*32 + c] + smem[1024 + rI*32 + c] + smem[2048 + rI*32 + c] + smem[3072 + rI*32 + c];
    v = fmaxf(v + bb, 0.f);
    if (g.C) {
      // fragment-major store: row = mt+rI, col = nt+c (one kblk: c<32)
      size_t off = ((size_t)((mt >> 4) + (rI >> 4)) * 24 + (nt >> 5)) * 512
                 + (size_t)(rI & 15) * 32 + (c >> 3) * 8 + (c & 7);
      g.C[off] = __hip_bfloat16(v);
    } else {
      smem[rI*32 + c] = v;
    }
  }
  __syncthreads();

  if (!g.C) {   // fused span head
    int rI = threadIdx.x >> 3, oi = threadIdx.x & 7;
    for (int o = oi; o < g.N; o += 8) {
      float s = 0.f;
      #pragma unroll
      for (int cc = 0; cc < 32; cc++) {
        int c2 = (cc + rI) & 31;
        s += smem[rI*32 + c2] * g.hw[(size_t)o * HD + nt + c2];
      }
      if (y == 0) s += g.hb[o];
      atomicAdd(g.outp + (size_t)(mt + rI) * g.N + o, s);
    }
  }
}

// ---------------------------------------------------------------------------
// GEMM layer 2: A AND W fragment-major bf16 -> all K-loop loads are
// contiguous 1 KB wave transactions. Exact 384-block grid, id = x*48 +
// (y+24z) (panel pinning, 48%8==0). Fused rel/cr heads.
// ---------------------------------------------------------------------------
struct P2 { const bf16* A; const bf16* W; const float* bias;
            const float *hw, *hb; float* outp; int N; };
struct P2x2 { P2 p[2]; };

__global__ __launch_bounds__(256, 2) void k_gemm2(P2x2 args)
{
  int id = blockIdx.x;
  int x = id / 48;
  int r48 = id % 48;
  int y = r48 % 24, z = r48 / 24;
  P2 g = args.p[z];
  int mt = x * 32, nt = y * 32;
  int wave = threadIdx.x >> 6, lane = threadIdx.x & 63;
  int lm = lane & 15, quad = lane >> 4;

  const bf16* a0p = g.A + (size_t)(mt >> 4) * 24 * 512 + lm * 32 + quad * 8;
  const bf16* a1p = a0p + 24 * 512;
  const bf16* w0p = g.W + (size_t)(nt >> 4) * 24 * 512 + lm * 32 + quad * 8;
  const bf16* w1p = w0p + 24 * 512;

  f32x4 acc00 = {0.f,0.f,0.f,0.f}, acc01 = {0.f,0.f,0.f,0.f};
  f32x4 acc10 = {0.f,0.f,0.f,0.f}, acc11 = {0.f,0.f,0.f,0.f};

  for (int k32 = wave * 32; k32 < HD; k32 += 128) {
    size_t fo = (size_t)k32 * 16;          // (k32/32)*512 elements
    short8 a0 = *(const short8*)(a0p + fo);
    short8 a1 = *(const short8*)(a1p + fo);
    short8 w0 = *(const short8*)(w0p + fo);
    short8 w1 = *(const short8*)(w1p + fo);
    acc00 = __builtin_amdgcn_mfma_f32_16x16x32_bf16(a0, w0, acc00, 0, 0, 0);
    acc01 = __builtin_amdgcn_mfma_f32_16x16x32_bf16(a0, w1, acc01, 0, 0, 0);
    acc10 = __builtin_amdgcn_mfma_f32_16x16x32_bf16(a1, w0, acc10, 0, 0, 0);
    acc11 = __builtin_amdgcn_mfma_f32_16x16x32_bf16(a1, w1, acc11, 0, 0, 0);
  }

  __shared__ float smem[4 * 32 * 32];
  #pragma unroll
  for (int reg = 0; reg < 4; reg++) {
    int rI = quad * 4 + reg;
    smem[wave*1024 + rI*32 + lm]             = acc00[reg];
    smem[wave*1024 + rI*32 + 16 + lm]        = acc01[reg];
    smem[wave*1024 + (16 + rI)*32 + lm]      = acc10[reg];
    smem[wave*1024 + (16 + rI)*32 + 16 + lm] = acc11[reg];
  }
  __syncthreads();

  int c = threadIdx.x & 31;
  int rb = threadIdx.x >> 5;
  float bb = g.bias[nt + c];
  #pragma unroll
  for (int i = 0; i < 4; i++) {
    int rI = rb + 8 * i;
    float v = smem[rI*32 + c] + smem[1024 + rI*32 + c] + smem[2048 + rI*32 + c] + smem[3072 + rI*32 + c];
    smem[rI*32 + c] = fmaxf(v + bb, 0.f);
  }
  __syncthreads();

  int rI = threadIdx.x >> 3, oi = threadIdx.x & 7;
  for (int o = oi; o < g.N; o += 8) {
    float s = 0.f;
    #pragma unroll
    for (int cc = 0; cc < 32; cc++) {
      int c2 = (cc + rI) & 31;
      s += smem[rI*32 + c2] * g.hw[(size_t)o * HD + nt + c2];
    }
    if (y == 0) s += g.hb[o];
    atomicAdd(g.outp + (size_t)(mt + rI) * g.N + o, s);
  }
}

// ---------------------------------------------------------------------------
extern "C" void kernel_launch(void* const* d_in, const int* in_sizes, int n_in,
                              void* d_out, int out_size, void* d_ws, size_t ws_size,
                              hipStream_t stream)
{
  const int*   input_ids  = (const int*)d_in[0];
  const int*   e_masks    = (const int*)d_in[1];
  const int*   e_sizes    = (const int*)d_in[2];
  const int*   m_masks    = (const int*)d_in[3];
  const int*   m_sizes    = (const int*)d_in[4];
  const int*   relations  = (const int*)d_in[5];
  const int*   r_masks    = (const int*)d_in[6];
  const int*   references = (const int*)d_in[7];
  const int*   c_masks    = (const int*)d_in[8];
  const float* emb        = (const float*)d_in[9];
  const float* nsemb      = (const float*)d_in[10];
  const float* esemb      = (const float*)d_in[11];
  const float* ner_rep_w  = (const float*)d_in[12];
  const float* ner_rep_b  = (const float*)d_in[13];
  const float* ner_head_w = (const float*)d_in[14];
  const float* ner_head_b = (const float*)d_in[15];
  const float* emd_rep_w  = (const float*)d_in[16];
  const float* emd_rep_b  = (const float*)d_in[17];
  const float* emd_head_w = (const float*)d_in[18];
  const float* emd_head_b = (const float*)d_in[19];
  const float* rel_w1 = (const float*)d_in[20];
  const float* rel_b1 = (const float*)d_in[21];
  const float* rel_w2 = (const float*)d_in[22];
  const float* rel_b2 = (const float*)d_in[23];
  const float* rel_w3 = (const float*)d_in[24];
  const float* rel_b3 = (const float*)d_in[25];
  const float* cr_w1 = (const float*)d_in[26];
  const float* cr_b1 = (const float*)d_in[27];
  const float* cr_w2 = (const float*)d_in[28];
  const float* cr_b2 = (const float*)d_in[29];
  const float* cr_w3 = (const float*)d_in[30];
  const float* cr_b3 = (const float*)d_in[31];
  float* out = (float*)d_out;

  // ---- workspace carve ----
  bf16* wsb = (bf16*)d_ws;
  size_t ob = 0;
  bf16* PART  = wsb + ob; ob += (size_t)NSPLIT * 768 * HD;
  bf16* EPOOL = wsb + ob; ob += (size_t)128 * HD;
  bf16* MPOOL = wsb + ob; ob += (size_t)128 * HD;
  bf16* RCTX  = wsb + ob; ob += (size_t)256 * HD;
  bf16* CCTX  = wsb + ob; ob += (size_t)256 * HD;
  bf16* SZE   = wsb + ob; ob += (size_t)128 * 32;
  bf16* SZM   = wsb + ob; ob += (size_t)128 * 32;
  bf16* CTXB  = wsb + ob; ob += (size_t)2 * HD;
  bf16* RH1   = wsb + ob; ob += (size_t)256 * HD;   // fragment-major [16][24][512]
  bf16* CH1   = wsb + ob; ob += (size_t)256 * HD;
  int*  FLAGS = (int*)(wsb + ob); ob += (size_t)2 * NSPLIT * 768;
  bf16* WB_NER = wsb + ob; ob += (size_t)HD * 1568;
  bf16* WB_EMD = wsb + ob; ob += (size_t)HD * 1568;
  bf16* WB_RW1 = wsb + ob; ob += (size_t)HD * 2368;
  bf16* WB_CW1 = wsb + ob; ob += (size_t)HD * 2368;
  bf16* WB_RW2 = wsb + ob; ob += (size_t)HD * HD;
  bf16* WB_CW2 = wsb + ob; ob += (size_t)HD * HD;

  WC6 wc;
  wc.c[0] = { ner_rep_w, WB_NER, 1568 };
  wc.c[1] = { emd_rep_w, WB_EMD, 1568 };
  wc.c[2] = { rel_w1,    WB_RW1, 2368 };
  wc.c[3] = { cr_w1,     WB_CW1, 2368 };
  wc.c[4] = { rel_w2,    WB_RW2, 768 };
  wc.c[5] = { cr_w2,     WB_CW2, 768 };

  // 1) pool partials + aux + fragment-major W convert
  k_d1<<<D1_BLOCKS, 256, 0, stream>>>(
      e_masks, m_masks, r_masks, c_masks, emb, input_ids,
      e_sizes, m_sizes, nsemb, esemb,
      PART, FLAGS, SZE, SZM, CTXB, out, wc);

  // 2) combine
  k_combine<<<768, 256, 0, stream>>>(PART, FLAGS, EPOOL, MPOOL, RCTX, CCTX);

  // 3) GEMM layer 1 (gathered A, fragment-major W) + fused span heads
  P1x4 a1;
  a1.p[0] = { CTXB, EPOOL, SZE, nullptr,    WB_NER, ner_rep_b,
              nullptr, ner_head_w, ner_head_b, out,        0, 10, 1568, 4 };
  a1.p[1] = { CTXB, MPOOL, SZM, nullptr,    WB_EMD, emd_rep_b,
              nullptr, emd_head_w, emd_head_b, out + 3328, 0, 2,  1568, 4 };
  a1.p[2] = { RCTX, EPOOL, SZE, relations,  WB_RW1, rel_b1,
              RH1, nullptr, nullptr, nullptr,              1, 0,  2368, 8 };
  a1.p[3] = { CCTX, MPOOL, SZM, references, WB_CW1, cr_b1,
              CH1, nullptr, nullptr, nullptr,              1, 0,  2368, 8 };
  k_gemm1<<<576, 256, 0, stream>>>(a1);

  // 4) GEMM layer 2 (fragment-major A and W) + fused rel/cr heads
  P2x2 a2;
  a2.p[0] = { RH1, WB_RW2, rel_b2, rel_w3, rel_b3, out + 1280, 8 };
  a2.p[1] = { CH1, WB_CW2, cr_b2,  cr_w3,  cr_b3,  out + 3584, 1 };
  k_gemm2<<<384, 256, 0, stream>>>(a2);
}